// Round 14
// baseline (358.024 us; speedup 1.0000x reference)
//
#include <hip/hip_runtime.h>
#include <math.h>

#define B_ 256
#define N_ 2048
#define D_ 128

#define NEG_HUGE (-1.0e30f)

// ws layout (floats): wsA [B][8][1040] attn partials (m[8], l[8], wsum[8][128])
//                     wsB [B][8][2] logits partials; wsC [B][128] c vector
//                     flags: 512 u32 (cprog[256], eprog[256])
#define WSA_STRIDE 1040
#define WSB_OFF (B_ * 8 * WSA_STRIDE)
#define WSC_OFF (WSB_OFF + B_ * 8 * 2)
#define FLAGS_OFF (WSC_OFF + B_ * D_)
#define WS_NEED_BYTES ((size_t)(FLAGS_OFF + 512) * 4)

typedef __attribute__((ext_vector_type(8))) short bf16x8;
typedef __attribute__((ext_vector_type(4))) float f32x4;
typedef __attribute__((ext_vector_type(4))) unsigned short u16x4;
typedef __attribute__((ext_vector_type(2))) int i32x2;

__device__ __forceinline__ float wave_max64(float v) {
#pragma unroll
  for (int off = 32; off > 0; off >>= 1) v = fmaxf(v, __shfl_xor(v, off, 64));
  return v;
}
__device__ __forceinline__ float wave_sum64(float v) {
#pragma unroll
  for (int off = 32; off > 0; off >>= 1) v += __shfl_xor(v, off, 64);
  return v;
}
__device__ __forceinline__ unsigned short bf16rne(float f) {
  unsigned u = __float_as_uint(f);
  u += 0x7FFFu + ((u >> 16) & 1u);
  return (unsigned short)(u >> 16);
}

// K1: per-(b, segment) mean partial sums -> buf[b][s*128 .. s*128+127].
__global__ void __launch_bounds__(256) k_prep(const float* __restrict__ emb,
                                              float* __restrict__ buf) {
  const int b = blockIdx.x, s = blockIdx.y, t = threadIdx.x;
  const int f4 = t & 31, g = t >> 5;
  const size_t rowbase = (size_t)b * N_;
  float4 acc = make_float4(0.f, 0.f, 0.f, 0.f);
  int n = s * 256 + g;
#pragma unroll 8
  for (int i = 0; i < 32; ++i, n += 8) {
    const float4 v = *(const float4*)(emb + (rowbase + n) * D_ + f4 * 4);
    acc.x += v.x; acc.y += v.y; acc.z += v.z; acc.w += v.w;
  }
  __shared__ float4 red[256];
  red[t] = acc;
  __syncthreads();
  if (g == 0) {
    float4 r = red[f4];
#pragma unroll
    for (int j = 1; j < 8; ++j) {
      const float4 a = red[j * 32 + f4];
      r.x += a.x; r.y += a.y; r.z += a.z; r.w += a.w;
    }
    *(float4*)(buf + (size_t)b * N_ + s * 128 + f4 * 4) = r;
  }
}

// K2: mean -> query -> qh (scale 0.25 folded) -> buf[b][1024..2047].
__global__ void __launch_bounds__(384) k_query(const float* __restrict__ emb,
                                               const float* __restrict__ Wfix,
                                               const float* __restrict__ Wstep,
                                               const float* __restrict__ Wnode,
                                               const int* __restrict__ fidx,
                                               const int* __restrict__ lidx,
                                               float* __restrict__ buf) {
  const int b = blockIdx.x, t = threadIdx.x;
  __shared__ float x[384];
  __shared__ float part[3][128];
  __shared__ float q[128];
  if (t < 128) {
    float ssum = 0.f;
#pragma unroll
    for (int i = 0; i < 8; ++i) ssum += buf[(size_t)b * N_ + i * 128 + t];
    x[t] = ssum * (1.0f / 2048.0f);
  } else if (t < 256) {
    x[t] = emb[((size_t)b * N_ + fidx[b]) * D_ + (t - 128)];
  } else {
    x[t] = emb[((size_t)b * N_ + lidx[b]) * D_ + (t - 256)];
  }
  __syncthreads();
  {
    const int seg = t >> 7, j = t & 127;
    const float* xs = &x[seg * 128];
    const float* Wp = (seg == 0) ? (Wfix + j) : (Wstep + (seg == 1 ? 0 : 128 * 128) + j);
    float acc = 0.f;
#pragma unroll 8
    for (int k = 0; k < 128; ++k) acc = fmaf(xs[k], Wp[(size_t)k * 128], acc);
    part[seg][j] = acc;
  }
  __syncthreads();
  if (t < 128) q[t] = part[0][t] + part[1][t] + part[2][t];
  __syncthreads();
  if (t < 128) {
    const float* wrow = Wnode + (size_t)t * 384;
#pragma unroll
    for (int h = 0; h < 8; ++h) {
      float a = 0.f;
#pragma unroll
      for (int k = 0; k < 16; ++k) a = fmaf(q[h * 16 + k], wrow[h * 16 + k], a);
      buf[(size_t)b * N_ + 1024 + h * 128 + t] = a * 0.25f;  // fold 1/sqrt(hd)
    }
  }
}

// K3: flash-attn partial (r8 body, verified) + last-arriver runs combine (D)
// inline. Spin-free: atomicAdd count; the 8th block for b has all partials
// visible (threadfence release before the add, acquire semantics after).
__global__ void __launch_bounds__(256) k_attn_m(const float* __restrict__ emb,
                                                const unsigned char* __restrict__ mask,
                                                const float* __restrict__ buf,
                                                const float* __restrict__ Wnode,
                                                const float* __restrict__ Wout,
                                                float* __restrict__ wsA,
                                                float* __restrict__ wsC,
                                                unsigned* __restrict__ cprog) {
  const int b = blockIdx.x, s = blockIdx.y;
  const int t = threadIdx.x;
  const int lane = t & 63, w = t >> 6;
  const int lg = lane >> 4, lc = lane & 15;
  __shared__ __align__(16) unsigned short eR[9216];
  __shared__ __align__(16) unsigned short pT[16 * 72];
  __shared__ float red0[64];
  __shared__ float red1[64];
  __shared__ float resc[16];
  __shared__ unsigned char mask_s[64];
  __shared__ unsigned sh_old;

  bf16x8 bq[4];
#pragma unroll
  for (int ks = 0; ks < 4; ++ks)
#pragma unroll
    for (int j = 0; j < 8; ++j) bq[ks][j] = 0;
  if (lc < 8) {
    const float* qrow = buf + (size_t)b * N_ + 1024 + lc * 128;
#pragma unroll
    for (int ks = 0; ks < 4; ++ks)
#pragma unroll
      for (int j = 0; j < 8; ++j)
        bq[ks][j] = (short)bf16rne(qrow[32 * ks + 8 * lg + j]);
  }
  float m_run = -INFINITY, l_run = 0.f;
  f32x4 wacc0 = {0.f, 0.f, 0.f, 0.f}, wacc1 = {0.f, 0.f, 0.f, 0.f};
  const float* embb = emb + ((size_t)b * N_ + s * 256) * D_;
  const unsigned char* mrow = mask + (size_t)b * N_ + s * 256;
  for (int tile = 0; tile < 4; ++tile) {
    {
      const float* src = embb + (size_t)tile * 64 * D_;
#pragma unroll
      for (int i = 0; i < 4; ++i) {
        const int gid = t + 256 * i;
        const int n = gid >> 4, d0 = (gid & 15) * 8;
        const float4 v0 = *(const float4*)(src + (size_t)n * D_ + d0);
        const float4 v1 = *(const float4*)(src + (size_t)n * D_ + d0 + 4);
        bf16x8 ev;
        ev[0] = (short)bf16rne(v0.x); ev[1] = (short)bf16rne(v0.y);
        ev[2] = (short)bf16rne(v0.z); ev[3] = (short)bf16rne(v0.w);
        ev[4] = (short)bf16rne(v1.x); ev[5] = (short)bf16rne(v1.y);
        ev[6] = (short)bf16rne(v1.z); ev[7] = (short)bf16rne(v1.w);
        const int widx = ((n >> 2) * 8 + (d0 >> 4)) * 72 + ((n & 3) << 4) + (d0 & 15);
        *(bf16x8*)&eR[widx] = ev;
      }
      if (t < 64) mask_s[t] = mrow[tile * 64 + t];
    }
    __syncthreads();
    f32x4 sAcc = {0.f, 0.f, 0.f, 0.f};
#pragma unroll
    for (int ks = 0; ks < 4; ++ks) {
      const int aidx = ((4 * w + (lc >> 2)) * 8 + 2 * ks + (lg >> 1)) * 72 +
                       ((lc & 3) << 4) + ((lg & 1) << 3);
      const bf16x8 af = *(const bf16x8*)&eR[aidx];
      sAcc = __builtin_amdgcn_mfma_f32_16x16x32_bf16(af, bq[ks], sAcc, 0, 0, 0);
    }
    float sv[4];
    bool mk[4];
    float tmax = -INFINITY;
#pragma unroll
    for (int r = 0; r < 4; ++r) {
      mk[r] = mask_s[16 * w + 4 * lg + r] != 0;
      sv[r] = mk[r] ? -INFINITY : sAcc[r];
      tmax = fmaxf(tmax, sv[r]);
    }
    tmax = fmaxf(tmax, __shfl_xor(tmax, 16, 64));
    tmax = fmaxf(tmax, __shfl_xor(tmax, 32, 64));
    if (lane < 16) red0[w * 16 + lc] = tmax;
    __syncthreads();
    const float m_tile = fmaxf(fmaxf(red0[lc], red0[16 + lc]),
                               fmaxf(red0[32 + lc], red0[48 + lc]));
    const float m_new = fmaxf(m_run, m_tile);
    const float rsc = (m_new == -INFINITY) ? 1.f : __expf(m_run - m_new);
    float psum = 0.f;
    unsigned short pu[4];
#pragma unroll
    for (int r = 0; r < 4; ++r) {
      const float p = mk[r] ? 0.f : __expf(sv[r] - m_new);
      psum += p;
      pu[r] = bf16rne(p);
    }
    m_run = m_new;
    psum += __shfl_xor(psum, 16, 64);
    psum += __shfl_xor(psum, 32, 64);
    if (lane < 16) red1[w * 16 + lc] = psum;
    *(u16x4*)&pT[lc * 72 + 16 * w + 4 * lg] = (u16x4){pu[0], pu[1], pu[2], pu[3]};
    if (t < 16) resc[t] = rsc;
    __syncthreads();
    l_run = l_run * rsc + (red1[lc] + red1[16 + lc] + red1[32 + lc] + red1[48 + lc]);
    {
      const float r0f = resc[4 * lg + 0], r1f = resc[4 * lg + 1];
      const float r2f = resc[4 * lg + 2], r3f = resc[4 * lg + 3];
      wacc0[0] *= r0f; wacc0[1] *= r1f; wacc0[2] *= r2f; wacc0[3] *= r3f;
      wacc1[0] *= r0f; wacc1[1] *= r1f; wacc1[2] *= r2f; wacc1[3] *= r3f;
    }
    i32x2 tb0a, tb0b, tb1a, tb1b, tb2a, tb2b, tb3a, tb3b;
    {
      const unsigned base00 = (unsigned)(unsigned long long)
          &eR[((0 + 2 * lg) * 8 + w) * 72 + lc];
      const unsigned base01 = (unsigned)(unsigned long long)
          &eR[((0 + 2 * lg) * 8 + (w + 4)) * 72 + lc];
      const unsigned base10 = (unsigned)(unsigned long long)
          &eR[((8 + 2 * lg) * 8 + w) * 72 + lc];
      const unsigned base11 = (unsigned)(unsigned long long)
          &eR[((8 + 2 * lg) * 8 + (w + 4)) * 72 + lc];
      asm volatile("ds_read_b64_tr_b16 %0, %2 offset:0\n\t"
                   "ds_read_b64_tr_b16 %1, %2 offset:1152"
                   : "=v"(tb0a), "=v"(tb0b) : "v"(base00));
      asm volatile("ds_read_b64_tr_b16 %0, %2 offset:0\n\t"
                   "ds_read_b64_tr_b16 %1, %2 offset:1152"
                   : "=v"(tb1a), "=v"(tb1b) : "v"(base01));
      asm volatile("ds_read_b64_tr_b16 %0, %2 offset:0\n\t"
                   "ds_read_b64_tr_b16 %1, %2 offset:1152"
                   : "=v"(tb2a), "=v"(tb2b) : "v"(base10));
      asm volatile("ds_read_b64_tr_b16 %0, %2 offset:0\n\t"
                   "ds_read_b64_tr_b16 %1, %2 offset:1152"
                   : "=v"(tb3a), "=v"(tb3b) : "v"(base11));
      asm volatile("s_waitcnt lgkmcnt(0)" ::: "memory");
      __builtin_amdgcn_sched_barrier(0);
    }
    {
      const bf16x8 pa0 = *(const bf16x8*)&pT[lc * 72 + 8 * lg];
      const bf16x8 pa1 = *(const bf16x8*)&pT[lc * 72 + 32 + 8 * lg];
      union { i32x2 d[2]; bf16x8 v; } u;
      u.d[0] = tb0a; u.d[1] = tb0b;
      wacc0 = __builtin_amdgcn_mfma_f32_16x16x32_bf16(pa0, u.v, wacc0, 0, 0, 0);
      u.d[0] = tb1a; u.d[1] = tb1b;
      wacc1 = __builtin_amdgcn_mfma_f32_16x16x32_bf16(pa0, u.v, wacc1, 0, 0, 0);
      u.d[0] = tb2a; u.d[1] = tb2b;
      wacc0 = __builtin_amdgcn_mfma_f32_16x16x32_bf16(pa1, u.v, wacc0, 0, 0, 0);
      u.d[0] = tb3a; u.d[1] = tb3b;
      wacc1 = __builtin_amdgcn_mfma_f32_16x16x32_bf16(pa1, u.v, wacc1, 0, 0, 0);
    }
    __syncthreads();
  }
  float* dst = wsA + (size_t)(b * 8 + s) * WSA_STRIDE;
  if (lg < 2) {
#pragma unroll
    for (int r = 0; r < 4; ++r) {
      const int h = 4 * lg + r;
      dst[16 + h * 128 + 16 * w + lc] = wacc0[r];
      dst[16 + h * 128 + 16 * (w + 4) + lc] = wacc1[r];
    }
  }
  if (t < 8) { dst[t] = m_run; dst[8 + t] = l_run; }
  __syncthreads();
  if (t == 0) { __threadfence(); sh_old = atomicAdd(&cprog[b], 1u); }
  __syncthreads();

  // ---- last arriver for b runs combine (D) inline ----
  if (sh_old == 7u) {
    __threadfence();
    float* Ls = red0;               // reuse small LDS
    float* scale = red1;            // 64 floats
    float* wl = (float*)eR;         // 1024 floats in big LDS
    float* heads = wl + 1024;
    float* glim = heads + 128;
    float* p2 = glim + 128;
    const int j = t & 127, hh = t >> 7;
    const float* base = wsA + (size_t)b * 8 * WSA_STRIDE;
    if (t < 8) {
      float M = -INFINITY;
#pragma unroll
      for (int q = 0; q < 8; ++q) M = fmaxf(M, base[q * WSA_STRIDE + t]);
      float L = 0.f;
#pragma unroll
      for (int q = 0; q < 8; ++q) {
        const float m = base[q * WSA_STRIDE + t];
        const float sc = (m == -INFINITY) ? 0.f : __expf(m - M);
        scale[q * 8 + t] = sc;
        L = fmaf(base[q * WSA_STRIDE + 8 + t], sc, L);
      }
      Ls[t] = L;
    }
    __syncthreads();
#pragma unroll
    for (int k = 0; k < 4; ++k) {
      const int idx = t + 256 * k;
      const int h = idx >> 7, d = idx & 127;
      float acc = 0.f;
#pragma unroll
      for (int q = 0; q < 8; ++q)
        acc = fmaf(scale[q * 8 + h], base[q * WSA_STRIDE + 16 + h * 128 + d], acc);
      wl[idx] = acc;
    }
    __syncthreads();
    {
      const int h = j >> 4, kk = j & 15;
      const float* wp = Wnode + 128 + h * 16 + kk;
      float acc = 0.f;
#pragma unroll 8
      for (int d = 64 * hh; d < 64 * hh + 64; ++d)
        acc = fmaf(wl[h * 128 + d], wp[(size_t)d * 384], acc);
      p2[hh * 128 + j] = acc;
    }
    __syncthreads();
    if (t < 128) heads[t] = (p2[t] + p2[128 + t]) / Ls[t >> 4];
    __syncthreads();
    {
      float acc = 0.f;
#pragma unroll 8
      for (int k = 64 * hh; k < 64 * hh + 64; ++k)
        acc = fmaf(heads[k], Wout[(size_t)k * 128 + j], acc);
      p2[hh * 128 + j] = acc;
    }
    __syncthreads();
    if (t < 128) glim[t] = p2[t] + p2[128 + t];
    __syncthreads();
    {
      const float* wr = Wnode + (size_t)j * 384 + 256;
      float acc = 0.f;
#pragma unroll 8
      for (int k = 64 * hh; k < 64 * hh + 64; ++k) acc = fmaf(wr[k], glim[k], acc);
      p2[hh * 128 + j] = acc;
    }
    __syncthreads();
    if (t < 128)
      wsC[(size_t)b * 128 + t] = (p2[t] + p2[128 + t]) * 0.08838834764831845f;
  }
}

// K4: logits partial (r8 body) + last-arriver runs normalize (F) inline.
__global__ void __launch_bounds__(256) k_logits_part(const float* __restrict__ emb,
                                                     const unsigned char* __restrict__ mask,
                                                     const float* __restrict__ wsC,
                                                     float* __restrict__ buf,
                                                     float* __restrict__ wsB,
                                                     unsigned* __restrict__ eprog) {
  const int b = blockIdx.x, s = blockIdx.y;
  const int t = threadIdx.x, lane = t & 63, w = t >> 6;
  __shared__ float lg[64];
  __shared__ unsigned sh_old;
  const float4 cf = ((const float4*)(wsC + (size_t)b * 128))[t & 31];
  const float* embb = emb + ((size_t)b * N_ + s * 256) * D_;
  const unsigned char* mrow = mask + (size_t)b * N_ + s * 256;
  float mr = NEG_HUGE, sr = 0.f;
  for (int tile = 0; tile < 4; ++tile) {
    const int n0 = tile * 64;
#pragma unroll
    for (int i = 0; i < 8; ++i) {
      const int gid = t + 256 * i;
      const int r = gid >> 5, c = (gid & 31) * 4;
      const float4 e = *(const float4*)(embb + (size_t)(n0 + r) * D_ + c);
      float p = fmaf(e.x, cf.x, fmaf(e.y, cf.y, fmaf(e.z, cf.z, e.w * cf.w)));
      p += __shfl_xor(p, 16, 64);
      p += __shfl_xor(p, 8, 64);
      p += __shfl_xor(p, 4, 64);
      p += __shfl_xor(p, 2, 64);
      p += __shfl_xor(p, 1, 64);
      if ((t & 31) == 0) lg[r] = p;
    }
    __syncthreads();
    const bool mk = mrow[n0 + lane] != 0;
    const float x = lg[lane];
    const float ex = __expf(2.f * x);
    const float val = mk ? NEG_HUGE : (10.f - __fdividef(20.f, ex + 1.f));
    const float tm = wave_max64(val);
    const float mn = fmaxf(mr, tm);
    sr = sr * __expf(mr - mn) + wave_sum64(mk ? 0.f : __expf(val - mn));
    mr = mn;
    if (w == 0) buf[(size_t)b * N_ + s * 256 + n0 + lane] = val;
    __syncthreads();
  }
  if (t == 0) {
    wsB[(size_t)(b * 8 + s) * 2] = mr;
    wsB[(size_t)(b * 8 + s) * 2 + 1] = sr;
  }
  __syncthreads();
  if (t == 0) { __threadfence(); sh_old = atomicAdd(&eprog[b], 1u); }
  __syncthreads();

  // ---- last arriver for b normalizes all 2048 entries of row b ----
  if (sh_old == 7u) {
    __threadfence();
    float M = NEG_HUGE;
#pragma unroll
    for (int q = 0; q < 8; ++q) M = fmaxf(M, wsB[(size_t)(b * 8 + q) * 2]);
    float S = 0.f;
#pragma unroll
    for (int q = 0; q < 8; ++q) {
      const float m = wsB[(size_t)(b * 8 + q) * 2];
      S += wsB[(size_t)(b * 8 + q) * 2 + 1] * __expf(m - M);
    }
    const float LS = M + logf(S);
#pragma unroll
    for (int i = 0; i < 8; ++i) {
      const size_t idx = (size_t)b * N_ + i * 256 + t;
      const float v = buf[idx];
      buf[idx] = (v <= -1.0e29f) ? NEG_HUGE : (v - LS);
    }
  }
}

extern "C" void kernel_launch(void* const* d_in, const int* in_sizes, int n_in,
                              void* d_out, int out_size, void* d_ws, size_t ws_size,
                              hipStream_t stream) {
  (void)in_sizes; (void)n_in; (void)out_size; (void)ws_size;
  const float* emb = (const float*)d_in[0];
  const float* Wnode = (const float*)d_in[1];
  const float* Wfix = (const float*)d_in[2];
  const float* Wstep = (const float*)d_in[3];
  const float* Wout = (const float*)d_in[4];
  const int* fidx = (const int*)d_in[5];
  const int* lidx = (const int*)d_in[6];
  const unsigned char* mask = (const unsigned char*)d_in[7];
  float* buf = (float*)d_out;
  float* ws = (float*)d_ws;
  unsigned* flg = (unsigned*)(ws + FLAGS_OFF);

  hipMemsetAsync(flg, 0, 512 * 4, stream);  // cprog/eprog must start at 0
  k_prep<<<dim3(B_, 8), 256, 0, stream>>>(emb, buf);
  k_query<<<B_, 384, 0, stream>>>(emb, Wfix, Wstep, Wnode, fidx, lidx, buf);
  k_attn_m<<<dim3(B_, 8), 256, 0, stream>>>(emb, mask, buf, Wnode, Wout, ws,
                                            ws + WSC_OFF, flg);
  k_logits_part<<<dim3(B_, 8), 256, 0, stream>>>(emb, mask, ws + WSC_OFF, buf,
                                                 ws + WSB_OFF, flg + 256);
}

// Round 15
// 160.105 us; speedup vs baseline: 2.2362x; 2.2362x over previous
//
#include <hip/hip_runtime.h>
#include <math.h>

#define B_ 256
#define N_ 2048
#define D_ 128

#define NEG_HUGE (-1.0e30f)

// ws layout (floats): wsA [B][8][1040] attn partials (m[8], l[8], wsum[8][128])
//                     wsB [B][8][2] logits partials; wsC [B][128] c vector
#define WSA_STRIDE 1040
#define WSB_OFF (B_ * 8 * WSA_STRIDE)
#define WSC_OFF (WSB_OFF + B_ * 8 * 2)

typedef __attribute__((ext_vector_type(8))) short bf16x8;
typedef __attribute__((ext_vector_type(4))) float f32x4;
typedef __attribute__((ext_vector_type(4))) unsigned short u16x4;
typedef __attribute__((ext_vector_type(2))) int i32x2;

__device__ __forceinline__ float wave_max64(float v) {
#pragma unroll
  for (int off = 32; off > 0; off >>= 1) v = fmaxf(v, __shfl_xor(v, off, 64));
  return v;
}
__device__ __forceinline__ float wave_sum64(float v) {
#pragma unroll
  for (int off = 32; off > 0; off >>= 1) v += __shfl_xor(v, off, 64);
  return v;
}
__device__ __forceinline__ unsigned short bf16rne(float f) {
  unsigned u = __float_as_uint(f);
  u += 0x7FFFu + ((u >> 16) & 1u);
  return (unsigned short)(u >> 16);
}

// K1: per-(b, segment) mean partial sums -> buf[b][s*128 .. s*128+127].
__global__ void __launch_bounds__(256) k_prep(const float* __restrict__ emb,
                                              float* __restrict__ buf) {
  const int b = blockIdx.x, s = blockIdx.y, t = threadIdx.x;
  const int f4 = t & 31, g = t >> 5;
  const size_t rowbase = (size_t)b * N_;
  float4 acc = make_float4(0.f, 0.f, 0.f, 0.f);
  int n = s * 256 + g;
#pragma unroll 8
  for (int i = 0; i < 32; ++i, n += 8) {
    const float4 v = *(const float4*)(emb + (rowbase + n) * D_ + f4 * 4);
    acc.x += v.x; acc.y += v.y; acc.z += v.z; acc.w += v.w;
  }
  __shared__ float4 red[256];
  red[t] = acc;
  __syncthreads();
  if (g == 0) {
    float4 r = red[f4];
#pragma unroll
    for (int j = 1; j < 8; ++j) {
      const float4 a = red[j * 32 + f4];
      r.x += a.x; r.y += a.y; r.z += a.z; r.w += a.w;
    }
    *(float4*)(buf + (size_t)b * N_ + s * 128 + f4 * 4) = r;
  }
}

// K2: mean -> query -> qh (scale 0.25 folded) -> buf[b][1024..2047].
__global__ void __launch_bounds__(384) k_query(const float* __restrict__ emb,
                                               const float* __restrict__ Wfix,
                                               const float* __restrict__ Wstep,
                                               const float* __restrict__ Wnode,
                                               const int* __restrict__ fidx,
                                               const int* __restrict__ lidx,
                                               float* __restrict__ buf) {
  const int b = blockIdx.x, t = threadIdx.x;
  __shared__ float x[384];
  __shared__ float part[3][128];
  __shared__ float q[128];
  if (t < 128) {
    float ssum = 0.f;
#pragma unroll
    for (int i = 0; i < 8; ++i) ssum += buf[(size_t)b * N_ + i * 128 + t];
    x[t] = ssum * (1.0f / 2048.0f);
  } else if (t < 256) {
    x[t] = emb[((size_t)b * N_ + fidx[b]) * D_ + (t - 128)];
  } else {
    x[t] = emb[((size_t)b * N_ + lidx[b]) * D_ + (t - 256)];
  }
  __syncthreads();
  {
    const int seg = t >> 7, j = t & 127;
    const float* xs = &x[seg * 128];
    const float* Wp = (seg == 0) ? (Wfix + j) : (Wstep + (seg == 1 ? 0 : 128 * 128) + j);
    float acc = 0.f;
#pragma unroll 8
    for (int k = 0; k < 128; ++k) acc = fmaf(xs[k], Wp[(size_t)k * 128], acc);
    part[seg][j] = acc;
  }
  __syncthreads();
  if (t < 128) q[t] = part[0][t] + part[1][t] + part[2][t];
  __syncthreads();
  if (t < 128) {
    const float* wrow = Wnode + (size_t)t * 384;
#pragma unroll
    for (int h = 0; h < 8; ++h) {
      float a = 0.f;
#pragma unroll
      for (int k = 0; k < 16; ++k) a = fmaf(q[h * 16 + k], wrow[h * 16 + k], a);
      buf[(size_t)b * N_ + 1024 + h * 128 + t] = a * 0.25f;  // fold 1/sqrt(hd)
    }
  }
}

// K3a (MFMA): flash-attn partial over a 256-node segment. Grid (B,8), 4 waves.
// eR subtiled [n/4][d/16][4][16] u16, 72-u16 subtile stride; wsum B-operand via
// ds_read_b64_tr_b16. Verified r5-r14.
__global__ void __launch_bounds__(256) k_attn_m(const float* __restrict__ emb,
                                                const unsigned char* __restrict__ mask,
                                                const float* __restrict__ buf,
                                                float* __restrict__ wsA) {
  const int b = blockIdx.x, s = blockIdx.y;
  const int t = threadIdx.x;
  const int lane = t & 63, w = t >> 6;
  const int lg = lane >> 4, lc = lane & 15;
  __shared__ __align__(16) unsigned short eR[9216];
  __shared__ __align__(16) unsigned short pT[16 * 72];
  __shared__ float red0[64];
  __shared__ float red1[64];
  __shared__ float resc[16];
  __shared__ unsigned char mask_s[64];

  bf16x8 bq[4];
#pragma unroll
  for (int ks = 0; ks < 4; ++ks)
#pragma unroll
    for (int j = 0; j < 8; ++j) bq[ks][j] = 0;
  if (lc < 8) {
    const float* qrow = buf + (size_t)b * N_ + 1024 + lc * 128;
#pragma unroll
    for (int ks = 0; ks < 4; ++ks)
#pragma unroll
      for (int j = 0; j < 8; ++j)
        bq[ks][j] = (short)bf16rne(qrow[32 * ks + 8 * lg + j]);
  }
  float m_run = -INFINITY, l_run = 0.f;
  f32x4 wacc0 = {0.f, 0.f, 0.f, 0.f}, wacc1 = {0.f, 0.f, 0.f, 0.f};
  const float* embb = emb + ((size_t)b * N_ + s * 256) * D_;
  const unsigned char* mrow = mask + (size_t)b * N_ + s * 256;
  for (int tile = 0; tile < 4; ++tile) {
    {
      const float* src = embb + (size_t)tile * 64 * D_;
#pragma unroll
      for (int i = 0; i < 4; ++i) {
        const int gid = t + 256 * i;
        const int n = gid >> 4, d0 = (gid & 15) * 8;
        const float4 v0 = *(const float4*)(src + (size_t)n * D_ + d0);
        const float4 v1 = *(const float4*)(src + (size_t)n * D_ + d0 + 4);
        bf16x8 ev;
        ev[0] = (short)bf16rne(v0.x); ev[1] = (short)bf16rne(v0.y);
        ev[2] = (short)bf16rne(v0.z); ev[3] = (short)bf16rne(v0.w);
        ev[4] = (short)bf16rne(v1.x); ev[5] = (short)bf16rne(v1.y);
        ev[6] = (short)bf16rne(v1.z); ev[7] = (short)bf16rne(v1.w);
        const int widx = ((n >> 2) * 8 + (d0 >> 4)) * 72 + ((n & 3) << 4) + (d0 & 15);
        *(bf16x8*)&eR[widx] = ev;
      }
      if (t < 64) mask_s[t] = mrow[tile * 64 + t];
    }
    __syncthreads();
    f32x4 sAcc = {0.f, 0.f, 0.f, 0.f};
#pragma unroll
    for (int ks = 0; ks < 4; ++ks) {
      const int aidx = ((4 * w + (lc >> 2)) * 8 + 2 * ks + (lg >> 1)) * 72 +
                       ((lc & 3) << 4) + ((lg & 1) << 3);
      const bf16x8 af = *(const bf16x8*)&eR[aidx];
      sAcc = __builtin_amdgcn_mfma_f32_16x16x32_bf16(af, bq[ks], sAcc, 0, 0, 0);
    }
    float sv[4];
    bool mk[4];
    float tmax = -INFINITY;
#pragma unroll
    for (int r = 0; r < 4; ++r) {
      mk[r] = mask_s[16 * w + 4 * lg + r] != 0;
      sv[r] = mk[r] ? -INFINITY : sAcc[r];
      tmax = fmaxf(tmax, sv[r]);
    }
    tmax = fmaxf(tmax, __shfl_xor(tmax, 16, 64));
    tmax = fmaxf(tmax, __shfl_xor(tmax, 32, 64));
    if (lane < 16) red0[w * 16 + lc] = tmax;
    __syncthreads();
    const float m_tile = fmaxf(fmaxf(red0[lc], red0[16 + lc]),
                               fmaxf(red0[32 + lc], red0[48 + lc]));
    const float m_new = fmaxf(m_run, m_tile);
    const float rsc = (m_new == -INFINITY) ? 1.f : __expf(m_run - m_new);
    float psum = 0.f;
    unsigned short pu[4];
#pragma unroll
    for (int r = 0; r < 4; ++r) {
      const float p = mk[r] ? 0.f : __expf(sv[r] - m_new);
      psum += p;
      pu[r] = bf16rne(p);
    }
    m_run = m_new;
    psum += __shfl_xor(psum, 16, 64);
    psum += __shfl_xor(psum, 32, 64);
    if (lane < 16) red1[w * 16 + lc] = psum;
    *(u16x4*)&pT[lc * 72 + 16 * w + 4 * lg] = (u16x4){pu[0], pu[1], pu[2], pu[3]};
    if (t < 16) resc[t] = rsc;
    __syncthreads();
    l_run = l_run * rsc + (red1[lc] + red1[16 + lc] + red1[32 + lc] + red1[48 + lc]);
    {
      const float r0f = resc[4 * lg + 0], r1f = resc[4 * lg + 1];
      const float r2f = resc[4 * lg + 2], r3f = resc[4 * lg + 3];
      wacc0[0] *= r0f; wacc0[1] *= r1f; wacc0[2] *= r2f; wacc0[3] *= r3f;
      wacc1[0] *= r0f; wacc1[1] *= r1f; wacc1[2] *= r2f; wacc1[3] *= r3f;
    }
    i32x2 tb0a, tb0b, tb1a, tb1b, tb2a, tb2b, tb3a, tb3b;
    {
      const unsigned base00 = (unsigned)(unsigned long long)
          &eR[((0 + 2 * lg) * 8 + w) * 72 + lc];
      const unsigned base01 = (unsigned)(unsigned long long)
          &eR[((0 + 2 * lg) * 8 + (w + 4)) * 72 + lc];
      const unsigned base10 = (unsigned)(unsigned long long)
          &eR[((8 + 2 * lg) * 8 + w) * 72 + lc];
      const unsigned base11 = (unsigned)(unsigned long long)
          &eR[((8 + 2 * lg) * 8 + (w + 4)) * 72 + lc];
      asm volatile("ds_read_b64_tr_b16 %0, %2 offset:0\n\t"
                   "ds_read_b64_tr_b16 %1, %2 offset:1152"
                   : "=v"(tb0a), "=v"(tb0b) : "v"(base00));
      asm volatile("ds_read_b64_tr_b16 %0, %2 offset:0\n\t"
                   "ds_read_b64_tr_b16 %1, %2 offset:1152"
                   : "=v"(tb1a), "=v"(tb1b) : "v"(base01));
      asm volatile("ds_read_b64_tr_b16 %0, %2 offset:0\n\t"
                   "ds_read_b64_tr_b16 %1, %2 offset:1152"
                   : "=v"(tb2a), "=v"(tb2b) : "v"(base10));
      asm volatile("ds_read_b64_tr_b16 %0, %2 offset:0\n\t"
                   "ds_read_b64_tr_b16 %1, %2 offset:1152"
                   : "=v"(tb3a), "=v"(tb3b) : "v"(base11));
      asm volatile("s_waitcnt lgkmcnt(0)" ::: "memory");
      __builtin_amdgcn_sched_barrier(0);
    }
    {
      const bf16x8 pa0 = *(const bf16x8*)&pT[lc * 72 + 8 * lg];
      const bf16x8 pa1 = *(const bf16x8*)&pT[lc * 72 + 32 + 8 * lg];
      union { i32x2 d[2]; bf16x8 v; } u;
      u.d[0] = tb0a; u.d[1] = tb0b;
      wacc0 = __builtin_amdgcn_mfma_f32_16x16x32_bf16(pa0, u.v, wacc0, 0, 0, 0);
      u.d[0] = tb1a; u.d[1] = tb1b;
      wacc1 = __builtin_amdgcn_mfma_f32_16x16x32_bf16(pa0, u.v, wacc1, 0, 0, 0);
      u.d[0] = tb2a; u.d[1] = tb2b;
      wacc0 = __builtin_amdgcn_mfma_f32_16x16x32_bf16(pa1, u.v, wacc0, 0, 0, 0);
      u.d[0] = tb3a; u.d[1] = tb3b;
      wacc1 = __builtin_amdgcn_mfma_f32_16x16x32_bf16(pa1, u.v, wacc1, 0, 0, 0);
    }
    __syncthreads();
  }
  float* dst = wsA + (size_t)(b * 8 + s) * WSA_STRIDE;
  if (lg < 2) {
#pragma unroll
    for (int r = 0; r < 4; ++r) {
      const int h = 4 * lg + r;
      dst[16 + h * 128 + 16 * w + lc] = wacc0[r];
      dst[16 + h * 128 + 16 * (w + 4) + lc] = wacc1[r];
    }
  }
  if (t < 8) { dst[t] = m_run; dst[8 + t] = l_run; }
}

// K3b: combine 8 segment partials -> heads -> glimpse -> c (to wsC).
__global__ void __launch_bounds__(256) k_attn_comb(const float* __restrict__ Wnode,
                                                   const float* __restrict__ Wout,
                                                   const float* __restrict__ wsA,
                                                   float* __restrict__ wsC) {
  const int b = blockIdx.x, t = threadIdx.x;
  const int j = t & 127, hh = t >> 7;
  const float* base = wsA + (size_t)b * 8 * WSA_STRIDE;
  __shared__ float Ls[8], scale[8][8];
  __shared__ float wl[8 * 128], heads[128], glim[128];
  __shared__ float part2[2][128];
  if (t < 8) {
    float M = -INFINITY;
#pragma unroll
    for (int s = 0; s < 8; ++s) M = fmaxf(M, base[s * WSA_STRIDE + t]);
    float L = 0.f;
#pragma unroll
    for (int s = 0; s < 8; ++s) {
      const float m = base[s * WSA_STRIDE + t];
      const float sc = (m == -INFINITY) ? 0.f : __expf(m - M);
      scale[s][t] = sc;
      L = fmaf(base[s * WSA_STRIDE + 8 + t], sc, L);
    }
    Ls[t] = L;
  }
  __syncthreads();
#pragma unroll
  for (int k = 0; k < 4; ++k) {
    const int idx = t + 256 * k;
    const int h = idx >> 7, d = idx & 127;
    float acc = 0.f;
#pragma unroll
    for (int s = 0; s < 8; ++s)
      acc = fmaf(scale[s][h], base[s * WSA_STRIDE + 16 + h * 128 + d], acc);
    wl[idx] = acc;
  }
  __syncthreads();
  {
    const int h = j >> 4, kk = j & 15;
    const float* wp = Wnode + 128 + h * 16 + kk;
    float acc = 0.f;
#pragma unroll 8
    for (int d = 64 * hh; d < 64 * hh + 64; ++d)
      acc = fmaf(wl[h * 128 + d], wp[(size_t)d * 384], acc);
    part2[hh][j] = acc;
  }
  __syncthreads();
  if (t < 128) heads[t] = (part2[0][t] + part2[1][t]) / Ls[t >> 4];
  __syncthreads();
  {
    float acc = 0.f;
#pragma unroll 8
    for (int k = 64 * hh; k < 64 * hh + 64; ++k)
      acc = fmaf(heads[k], Wout[(size_t)k * 128 + j], acc);
    part2[hh][j] = acc;
  }
  __syncthreads();
  if (t < 128) glim[t] = part2[0][t] + part2[1][t];
  __syncthreads();
  {
    const float* wr = Wnode + (size_t)j * 384 + 256;
    float acc = 0.f;
#pragma unroll 8
    for (int k = 64 * hh; k < 64 * hh + 64; ++k) acc = fmaf(wr[k], glim[k], acc);
    part2[hh][j] = acc;
  }
  __syncthreads();
  if (t < 128)
    wsC[(size_t)b * 128 + t] = (part2[0][t] + part2[1][t]) * 0.08838834764831845f;
}

// K4a: logits over a 256-node segment; running (max,sum) to wsB. Grid (B,8).
__global__ void __launch_bounds__(256) k_logits_part(const float* __restrict__ emb,
                                                     const unsigned char* __restrict__ mask,
                                                     const float* __restrict__ wsC,
                                                     float* __restrict__ buf,
                                                     float* __restrict__ wsB) {
  const int b = blockIdx.x, s = blockIdx.y;
  const int t = threadIdx.x, lane = t & 63, w = t >> 6;
  __shared__ float lg[64];
  const float4 cf = ((const float4*)(wsC + (size_t)b * 128))[t & 31];
  const float* embb = emb + ((size_t)b * N_ + s * 256) * D_;
  const unsigned char* mrow = mask + (size_t)b * N_ + s * 256;
  float mr = NEG_HUGE, sr = 0.f;
  for (int tile = 0; tile < 4; ++tile) {
    const int n0 = tile * 64;
#pragma unroll
    for (int i = 0; i < 8; ++i) {
      const int gid = t + 256 * i;
      const int r = gid >> 5, c = (gid & 31) * 4;
      const float4 e = *(const float4*)(embb + (size_t)(n0 + r) * D_ + c);
      float p = fmaf(e.x, cf.x, fmaf(e.y, cf.y, fmaf(e.z, cf.z, e.w * cf.w)));
      p += __shfl_xor(p, 16, 64);
      p += __shfl_xor(p, 8, 64);
      p += __shfl_xor(p, 4, 64);
      p += __shfl_xor(p, 2, 64);
      p += __shfl_xor(p, 1, 64);
      if ((t & 31) == 0) lg[r] = p;
    }
    __syncthreads();
    const bool mk = mrow[n0 + lane] != 0;
    const float x = lg[lane];
    const float ex = __expf(2.f * x);
    const float val = mk ? NEG_HUGE : (10.f - __fdividef(20.f, ex + 1.f));
    const float tm = wave_max64(val);
    const float mn = fmaxf(mr, tm);
    sr = sr * __expf(mr - mn) + wave_sum64(mk ? 0.f : __expf(val - mn));
    mr = mn;
    if (w == 0) buf[(size_t)b * N_ + s * 256 + n0 + lane] = val;
    __syncthreads();
  }
  if (t == 0) {
    wsB[(size_t)(b * 8 + s) * 2] = mr;
    wsB[(size_t)(b * 8 + s) * 2 + 1] = sr;
  }
}

// K4b: log-softmax normalization in place. Grid (B,8); per-thread redundant LS.
__global__ void __launch_bounds__(256) k_norm(const float* __restrict__ wsB,
                                              float* __restrict__ buf) {
  const int b = blockIdx.x, s = blockIdx.y, t = threadIdx.x;
  float M = NEG_HUGE;
#pragma unroll
  for (int q = 0; q < 8; ++q) M = fmaxf(M, wsB[(size_t)(b * 8 + q) * 2]);
  float S = 0.f;
#pragma unroll
  for (int q = 0; q < 8; ++q) {
    const float m = wsB[(size_t)(b * 8 + q) * 2];
    S += wsB[(size_t)(b * 8 + q) * 2 + 1] * __expf(m - M);
  }
  const float LS = M + logf(S);
  const size_t idx = (size_t)b * N_ + s * 256 + t;
  const float v = buf[idx];
  buf[idx] = (v <= -1.0e29f) ? NEG_HUGE : (v - LS);
}

extern "C" void kernel_launch(void* const* d_in, const int* in_sizes, int n_in,
                              void* d_out, int out_size, void* d_ws, size_t ws_size,
                              hipStream_t stream) {
  (void)in_sizes; (void)n_in; (void)out_size; (void)ws_size;
  const float* emb = (const float*)d_in[0];
  const float* Wnode = (const float*)d_in[1];
  const float* Wfix = (const float*)d_in[2];
  const float* Wstep = (const float*)d_in[3];
  const float* Wout = (const float*)d_in[4];
  const int* fidx = (const int*)d_in[5];
  const int* lidx = (const int*)d_in[6];
  const unsigned char* mask = (const unsigned char*)d_in[7];
  float* buf = (float*)d_out;
  float* ws = (float*)d_ws;

  k_prep<<<dim3(B_, 8), 256, 0, stream>>>(emb, buf);
  k_query<<<B_, 384, 0, stream>>>(emb, Wfix, Wstep, Wnode, fidx, lidx, buf);
  k_attn_m<<<dim3(B_, 8), 256, 0, stream>>>(emb, mask, buf, ws);
  k_attn_comb<<<B_, 256, 0, stream>>>(Wnode, Wout, ws, ws + WSC_OFF);
  k_logits_part<<<dim3(B_, 8), 256, 0, stream>>>(emb, mask, ws + WSC_OFF, buf, ws + WSB_OFF);
  k_norm<<<dim3(B_, 8), 256, 0, stream>>>(ws + WSB_OFF, buf);
}